// Round 1
// baseline (308.165 us; speedup 1.0000x reference)
//
#include <hip/hip_runtime.h>
#include <hip/hip_bf16.h>
#include <stdint.h>

// Problem constants
#define B_   2
#define S_   2048
#define DIN  1024
#define DOUT 1024
#define H_   16
#define DH_  64

typedef __bf16 bf16_t;
typedef bf16_t bf16x8 __attribute__((ext_vector_type(8)));
typedef float  f32x4  __attribute__((ext_vector_type(4)));

static __device__ __forceinline__ void gld_lds16(const void* g, void* l) {
  __builtin_amdgcn_global_load_lds((const __attribute__((address_space(1))) void*)g,
                                   (__attribute__((address_space(3))) void*)l, 16, 0, 0);
}

static __device__ __forceinline__ unsigned short f2bf(float f) {
  __hip_bfloat16 h = __float2bfloat16(f);
  return __builtin_bit_cast(unsigned short, h);
}

// ---------------- convert x (fp32 -> bf16), 4 elems/thread ----------------
__global__ __launch_bounds__(256) void k_convert_x(const float* __restrict__ x,
                                                   unsigned short* __restrict__ xb) {
  int i = (blockIdx.x * 256 + threadIdx.x) * 4;
  float4 v = *reinterpret_cast<const float4*>(x + i);
  ushort4 o;
  o.x = f2bf(v.x); o.y = f2bf(v.y); o.z = f2bf(v.z); o.w = f2bf(v.w);
  *reinterpret_cast<ushort4*>(xb + i) = o;
}

// ------------- transpose+convert W [K][N] fp32 -> Wt [N][K] bf16 -----------
__global__ __launch_bounds__(256) void k_transpose_w(const float* __restrict__ Wq,
                                                     const float* __restrict__ Wk,
                                                     const float* __restrict__ Wv,
                                                     const float* __restrict__ Wo,
                                                     __hip_bfloat16* __restrict__ Wt3,
                                                     __hip_bfloat16* __restrict__ Wot) {
  __shared__ float tile[32][33];
  const int z = blockIdx.z;
  const float* src = (z == 0) ? Wq : (z == 1) ? Wk : (z == 2) ? Wv : Wo;
  __hip_bfloat16* dst = (z < 3) ? (Wt3 + (size_t)z * DIN * DOUT) : Wot;
  const int n0 = blockIdx.x * 32, k0 = blockIdx.y * 32;
  const int tx = threadIdx.x, ty = threadIdx.y;   // block (32,8)
  #pragma unroll
  for (int i = ty; i < 32; i += 8)
    tile[i][tx] = src[(size_t)(k0 + i) * DOUT + n0 + tx];
  __syncthreads();
  #pragma unroll
  for (int i = ty; i < 32; i += 8)
    dst[(size_t)(n0 + i) * DIN + k0 + tx] = __float2bfloat16(tile[tx][i]);
}

// ---------------- GEMM: C[M,N] = A[M,K] * Bt[N,K]^T  (bf16 MFMA) ----------
// MODE 0: epilogue scatters to Q [b,h,s,dh], K [b,h,s,dh], Vt [b,h,dh,s] (bf16)
// MODE 1: epilogue writes fp32 Out[m*N+n] + bias[n]
template <int MODE>
__global__ __launch_bounds__(256) void k_gemm_bt(
    const __hip_bfloat16* __restrict__ A,    // [M][K]
    const __hip_bfloat16* __restrict__ Bt,   // [N][K]
    __hip_bfloat16* __restrict__ Qb, __hip_bfloat16* __restrict__ Kb,
    __hip_bfloat16* __restrict__ Vtb,
    float* __restrict__ Out, const float* __restrict__ bias,
    int M, int N, int K)
{
  __shared__ __align__(16) __hip_bfloat16 As[128 * 32];
  __shared__ __align__(16) __hip_bfloat16 Bs[128 * 32];
  const int tid = threadIdx.x;
  const int lane = tid & 63, wid = tid >> 6;
  const int r15 = lane & 15, g = lane >> 4;
  const int m0 = blockIdx.x * 128, n0 = blockIdx.y * 128;
  const int wr = wid >> 1, wc = wid & 1;          // wave owns 64x64 sub-tile
  f32x4 acc[4][4] = {};

  for (int kt = 0; kt < K; kt += 32) {
    #pragma unroll
    for (int i = 0; i < 2; ++i) {
      const int li = i * 256 + tid;               // 0..511, 16B each
      const int row = li >> 2, kb = (li & 3) * 8; // kb in elements
      gld_lds16(A  + (size_t)(m0 + row) * K + kt + kb, (void*)(As + (size_t)(li & ~63) * 8));
      gld_lds16(Bt + (size_t)(n0 + row) * K + kt + kb, (void*)(Bs + (size_t)(li & ~63) * 8));
    }
    __syncthreads();
    bf16x8 af[4], bfr[4];
    #pragma unroll
    for (int mi = 0; mi < 4; ++mi)
      af[mi] = *reinterpret_cast<const bf16x8*>(As + (wr * 64 + mi * 16 + r15) * 32 + g * 8);
    #pragma unroll
    for (int ni = 0; ni < 4; ++ni)
      bfr[ni] = *reinterpret_cast<const bf16x8*>(Bs + (wc * 64 + ni * 16 + r15) * 32 + g * 8);
    #pragma unroll
    for (int mi = 0; mi < 4; ++mi)
      #pragma unroll
      for (int ni = 0; ni < 4; ++ni)
        acc[mi][ni] = __builtin_amdgcn_mfma_f32_16x16x32_bf16(af[mi], bfr[ni], acc[mi][ni], 0, 0, 0);
    __syncthreads();
  }

  // Epilogue. C/D layout: col = lane&15, row = (lane>>4)*4 + reg  [verified m89/m91]
  #pragma unroll
  for (int mi = 0; mi < 4; ++mi) {
    #pragma unroll
    for (int ni = 0; ni < 4; ++ni) {
      #pragma unroll
      for (int rr = 0; rr < 4; ++rr) {
        const int m = m0 + wr * 64 + mi * 16 + g * 4 + rr;
        const int n = n0 + wc * 64 + ni * 16 + r15;
        const float v = acc[mi][ni][rr];
        if (MODE == 0) {
          const int w = n >> 10, nn = n & 1023;
          const int h = nn >> 6, dh = nn & 63;
          const int b = m >> 11, s = m & 2047;
          const __hip_bfloat16 hv = __float2bfloat16(v);
          const size_t bh = (size_t)(b * H_ + h);
          if (w == 0)      Qb [(bh * S_ + s) * DH_ + dh] = hv;
          else if (w == 1) Kb [(bh * S_ + s) * DH_ + dh] = hv;
          else             Vtb[(bh * DH_ + dh) * S_ + s] = hv;
        } else {
          Out[(size_t)m * N + n] = v + bias[n];
        }
      }
    }
  }
}

// ---------------- flash attention (causal, scale = 1/sqrt(S)) -------------
// grid (S/64, B*H); 4 waves/block, each wave owns 16 q-rows. KVBLK=64.
// K and Vt fragments read directly from global (K/V per head = 256KB, L2-fit).
__global__ __launch_bounds__(256) void k_attn(
    const __hip_bfloat16* __restrict__ Qb,
    const __hip_bfloat16* __restrict__ Kb,
    const __hip_bfloat16* __restrict__ Vtb,
    __hip_bfloat16* __restrict__ Ctx)
{
  __shared__ __align__(16) __hip_bfloat16 P[4][16][64];   // per-wave P tile (bf16)
  const int tid = threadIdx.x, lane = tid & 63, w = tid >> 6;
  const int r15 = lane & 15, g = lane >> 4;
  const int bh = blockIdx.y;
  const int b = bh >> 4, h = bh & 15;
  const int q0 = blockIdx.x * 64 + w * 16;
  const __hip_bfloat16* Qh = Qb  + (size_t)bh * S_ * DH_;
  const __hip_bfloat16* Kh = Kb  + (size_t)bh * S_ * DH_;
  const __hip_bfloat16* Vh = Vtb + (size_t)bh * DH_ * S_;
  const float scale = 0.022097086912079608f;  // 1/sqrt(2048)

  bf16x8 qf[2];
  #pragma unroll
  for (int ks = 0; ks < 2; ++ks)
    qf[ks] = *reinterpret_cast<const bf16x8*>(Qh + (size_t)(q0 + r15) * DH_ + ks * 32 + g * 8);

  f32x4 of[4] = {};                       // ctx accumulator [dh-frag][reg]
  float mrow[4], lrow[4], alpha[4];
  #pragma unroll
  for (int rr = 0; rr < 4; ++rr) { mrow[rr] = -INFINITY; lrow[rr] = 0.f; }

  const int tmax = (q0 + 15) >> 6;
  for (int t = 0; t <= tmax; ++t) {
    const int kv0 = t * 64;
    f32x4 sf[4] = {};
    #pragma unroll
    for (int ks = 0; ks < 2; ++ks)
      #pragma unroll
      for (int c = 0; c < 4; ++c) {
        bf16x8 kf = *reinterpret_cast<const bf16x8*>(
            Kh + (size_t)(kv0 + c * 16 + r15) * DH_ + ks * 32 + g * 8);
        sf[c] = __builtin_amdgcn_mfma_f32_16x16x32_bf16(qf[ks], kf, sf[c], 0, 0, 0);
      }

    // online softmax per reg (row = g*4 + rr); row's 16 cols live in the 16-lane group
    #pragma unroll
    for (int rr = 0; rr < 4; ++rr) {
      const int qg = q0 + g * 4 + rr;
      float vals[4], vmax = -INFINITY;
      #pragma unroll
      for (int c = 0; c < 4; ++c) {
        const int kg = kv0 + c * 16 + r15;
        const float sv = (kg <= qg) ? sf[c][rr] * scale : -INFINITY;
        vals[c] = sv;
        vmax = fmaxf(vmax, sv);
      }
      #pragma unroll
      for (int mm = 1; mm < 16; mm <<= 1)
        vmax = fmaxf(vmax, __shfl_xor(vmax, mm, 64));
      const float mnew = fmaxf(mrow[rr], vmax);
      const float a = __expf(mrow[rr] - mnew);    // exp(-inf)=0 on first tile
      float psum = 0.f;
      #pragma unroll
      for (int c = 0; c < 4; ++c) {
        const float p = __expf(vals[c] - mnew);
        psum += p;
        P[w][g * 4 + rr][c * 16 + r15] = __float2bfloat16(p);
      }
      #pragma unroll
      for (int mm = 1; mm < 16; mm <<= 1)
        psum += __shfl_xor(psum, mm, 64);
      lrow[rr] = lrow[rr] * a + psum;
      mrow[rr] = mnew;
      alpha[rr] = a;
    }
    #pragma unroll
    for (int d = 0; d < 4; ++d)
      #pragma unroll
      for (int rr = 0; rr < 4; ++rr)
        of[d][rr] *= alpha[rr];

    // PV: A = P (LDS), B = V via Vt[dh][s] (contiguous along s)
    #pragma unroll
    for (int ks = 0; ks < 2; ++ks) {
      bf16x8 pf = *reinterpret_cast<const bf16x8*>(&P[w][r15][ks * 32 + g * 8]);
      #pragma unroll
      for (int d = 0; d < 4; ++d) {
        bf16x8 vf = *reinterpret_cast<const bf16x8*>(
            Vh + (size_t)(d * 16 + r15) * S_ + kv0 + ks * 32 + g * 8);
        of[d] = __builtin_amdgcn_mfma_f32_16x16x32_bf16(pf, vf, of[d], 0, 0, 0);
      }
    }
  }

  // write ctx [b, s, h, dh] bf16
  #pragma unroll
  for (int rr = 0; rr < 4; ++rr) {
    const int qg = q0 + g * 4 + rr;
    const float inv = 1.0f / lrow[rr];
    #pragma unroll
    for (int d = 0; d < 4; ++d)
      Ctx[((size_t)(b * S_ + qg) * H_ + h) * DH_ + d * 16 + r15] =
          __float2bfloat16(of[d][rr] * inv);
  }
}

// --------------------------------- launch --------------------------------
extern "C" void kernel_launch(void* const* d_in, const int* in_sizes, int n_in,
                              void* d_out, int out_size, void* d_ws, size_t ws_size,
                              hipStream_t stream) {
  const float* x  = (const float*)d_in[0];
  const float* Wq = (const float*)d_in[1];
  const float* Wk = (const float*)d_in[2];
  const float* Wv = (const float*)d_in[3];
  const float* Wo = (const float*)d_in[4];
  const float* bo = (const float*)d_in[5];
  float* out = (float*)d_out;

  uint8_t* ws = (uint8_t*)d_ws;
  // layout (bytes): xb 8M | Wt3 6M | Wot 2M | Q 8M | K 8M | Vt 8M | Ctx 8M = 48MB
  __hip_bfloat16* xb  = (__hip_bfloat16*)(ws);
  __hip_bfloat16* Wt3 = (__hip_bfloat16*)(ws + 8388608);
  __hip_bfloat16* Wot = (__hip_bfloat16*)(ws + 14680064);
  __hip_bfloat16* Qb  = (__hip_bfloat16*)(ws + 16777216);
  __hip_bfloat16* Kb  = (__hip_bfloat16*)(ws + 25165824);
  __hip_bfloat16* Vtb = (__hip_bfloat16*)(ws + 33554432);
  __hip_bfloat16* Ctx = (__hip_bfloat16*)(ws + 41943040);

  k_convert_x<<<4096, 256, 0, stream>>>(x, (unsigned short*)xb);
  k_transpose_w<<<dim3(32, 32, 4), dim3(32, 8), 0, stream>>>(Wq, Wk, Wv, Wo, Wt3, Wot);
  // fused QKV: A = xb [4096,1024], Bt = [Wq^T|Wk^T|Wv^T] [3072,1024]
  k_gemm_bt<0><<<dim3(32, 24), 256, 0, stream>>>(xb, Wt3, Qb, Kb, Vtb, nullptr, nullptr,
                                                 4096, 3072, 1024);
  k_attn<<<dim3(32, 32), 256, 0, stream>>>(Qb, Kb, Vtb, Ctx);
  // out = Ctx @ Wo + bo  (fp32 out)
  k_gemm_bt<1><<<dim3(32, 8), 256, 0, stream>>>(Ctx, Wot, nullptr, nullptr, nullptr,
                                                out, bo, 4096, 1024, 1024);
}

// Round 2
// 153.833 us; speedup vs baseline: 2.0032x; 2.0032x over previous
//
#include <hip/hip_runtime.h>
#include <hip/hip_bf16.h>
#include <stdint.h>

// Problem constants
#define B_   2
#define S_   2048
#define DIN  1024
#define DOUT 1024
#define H_   16
#define DH_  64

typedef __bf16 bf16_t;
typedef bf16_t bf16x8 __attribute__((ext_vector_type(8)));
typedef float  f32x4  __attribute__((ext_vector_type(4)));

static __device__ __forceinline__ void gld_lds16(const void* g, void* l) {
  __builtin_amdgcn_global_load_lds((const __attribute__((address_space(1))) void*)g,
                                   (__attribute__((address_space(3))) void*)l, 16, 0, 0);
}

static __device__ __forceinline__ unsigned short f2bf(float f) {
  __hip_bfloat16 h = __float2bfloat16(f);
  return __builtin_bit_cast(unsigned short, h);
}

// ---------------- convert x (fp32 -> bf16), 4 elems/thread ----------------
__global__ __launch_bounds__(256) void k_convert_x(const float* __restrict__ x,
                                                   unsigned short* __restrict__ xb) {
  int i = (blockIdx.x * 256 + threadIdx.x) * 4;
  float4 v = *reinterpret_cast<const float4*>(x + i);
  ushort4 o;
  o.x = f2bf(v.x); o.y = f2bf(v.y); o.z = f2bf(v.z); o.w = f2bf(v.w);
  *reinterpret_cast<ushort4*>(xb + i) = o;
}

// ------------- transpose+convert W [K][N] fp32 -> Wt [N][K] bf16 -----------
__global__ __launch_bounds__(256) void k_transpose_w(const float* __restrict__ Wq,
                                                     const float* __restrict__ Wk,
                                                     const float* __restrict__ Wv,
                                                     const float* __restrict__ Wo,
                                                     __hip_bfloat16* __restrict__ Wt3,
                                                     __hip_bfloat16* __restrict__ Wot) {
  __shared__ float tile[32][33];
  const int z = blockIdx.z;
  const float* src = (z == 0) ? Wq : (z == 1) ? Wk : (z == 2) ? Wv : Wo;
  __hip_bfloat16* dst = (z < 3) ? (Wt3 + (size_t)z * DIN * DOUT) : Wot;
  const int n0 = blockIdx.x * 32, k0 = blockIdx.y * 32;
  const int tx = threadIdx.x, ty = threadIdx.y;   // block (32,8)
  #pragma unroll
  for (int i = ty; i < 32; i += 8)
    tile[i][tx] = src[(size_t)(k0 + i) * DOUT + n0 + tx];
  __syncthreads();
  #pragma unroll
  for (int i = ty; i < 32; i += 8)
    dst[(size_t)(n0 + i) * DIN + k0 + tx] = __float2bfloat16(tile[tx][i]);
}

// ---------------- GEMM: C[M,N] = A[M,K] * Bt[N,K]^T  (bf16 MFMA) ----------
// MODE 0: epilogue scatters to Q*scale [b,h,s,dh], K [b,h,s,dh], Vt [b,h,dh,s]
// MODE 1: epilogue writes fp32 Out[m*N+n] + bias[n]
template <int MODE>
__global__ __launch_bounds__(256) void k_gemm_bt(
    const __hip_bfloat16* __restrict__ A,    // [M][K]
    const __hip_bfloat16* __restrict__ Bt,   // [N][K]
    __hip_bfloat16* __restrict__ Qb, __hip_bfloat16* __restrict__ Kb,
    __hip_bfloat16* __restrict__ Vtb,
    float* __restrict__ Out, const float* __restrict__ bias,
    int M, int N, int K)
{
  __shared__ __align__(16) __hip_bfloat16 As[128 * 32];
  __shared__ __align__(16) __hip_bfloat16 Bs[128 * 32];
  const int tid = threadIdx.x;
  const int lane = tid & 63, wid = tid >> 6;
  const int r15 = lane & 15, g = lane >> 4;
  const int m0 = blockIdx.x * 128, n0 = blockIdx.y * 128;
  const int wr = wid >> 1, wc = wid & 1;          // wave owns 64x64 sub-tile
  f32x4 acc[4][4] = {};

  for (int kt = 0; kt < K; kt += 32) {
    #pragma unroll
    for (int i = 0; i < 2; ++i) {
      const int li = i * 256 + tid;               // 0..511, 16B each
      const int row = li >> 2, kb = (li & 3) * 8; // kb in elements
      gld_lds16(A  + (size_t)(m0 + row) * K + kt + kb, (void*)(As + (size_t)(li & ~63) * 8));
      gld_lds16(Bt + (size_t)(n0 + row) * K + kt + kb, (void*)(Bs + (size_t)(li & ~63) * 8));
    }
    __syncthreads();
    bf16x8 af[4], bfr[4];
    #pragma unroll
    for (int mi = 0; mi < 4; ++mi)
      af[mi] = *reinterpret_cast<const bf16x8*>(As + (wr * 64 + mi * 16 + r15) * 32 + g * 8);
    #pragma unroll
    for (int ni = 0; ni < 4; ++ni)
      bfr[ni] = *reinterpret_cast<const bf16x8*>(Bs + (wc * 64 + ni * 16 + r15) * 32 + g * 8);
    #pragma unroll
    for (int mi = 0; mi < 4; ++mi)
      #pragma unroll
      for (int ni = 0; ni < 4; ++ni)
        acc[mi][ni] = __builtin_amdgcn_mfma_f32_16x16x32_bf16(af[mi], bfr[ni], acc[mi][ni], 0, 0, 0);
    __syncthreads();
  }

  // Epilogue. C/D layout: col = lane&15, row = (lane>>4)*4 + reg  [verified m89/m91]
  #pragma unroll
  for (int mi = 0; mi < 4; ++mi) {
    #pragma unroll
    for (int ni = 0; ni < 4; ++ni) {
      #pragma unroll
      for (int rr = 0; rr < 4; ++rr) {
        const int m = m0 + wr * 64 + mi * 16 + g * 4 + rr;
        const int n = n0 + wc * 64 + ni * 16 + r15;
        float v = acc[mi][ni][rr];
        if (MODE == 0) {
          const int w = n >> 10, nn = n & 1023;
          const int h = nn >> 6, dh = nn & 63;
          const int b = m >> 11, s = m & 2047;
          if (w == 0) v *= 0.022097086912079608f;     // fold 1/sqrt(S) into Q
          const __hip_bfloat16 hv = __float2bfloat16(v);
          const size_t bh = (size_t)(b * H_ + h);
          if (w == 0)      Qb [(bh * S_ + s) * DH_ + dh] = hv;
          else if (w == 1) Kb [(bh * S_ + s) * DH_ + dh] = hv;
          else             Vtb[(bh * DH_ + dh) * S_ + s] = hv;
        } else {
          Out[(size_t)m * N + n] = v + bias[n];
        }
      }
    }
  }
}

// ---------------- flash attention (causal, swapped-operand QK^T) ----------
// grid (S/64, B*H); 4 waves/block, each wave owns 16 q-rows. KVBLK=64.
// K, Vt tiles cooperatively staged to LDS (double-buffered, XOR-swizzled).
// QK^T computed swapped: D[kv][q] -> each lane holds 16 kv values for ONE q
// (lane-local softmax: 4-deep trees + 2 shfl_xor instead of 32 shfls).
__global__ __launch_bounds__(256) void k_attn(
    const __hip_bfloat16* __restrict__ Qb,
    const __hip_bfloat16* __restrict__ Kb,
    const __hip_bfloat16* __restrict__ Vtb,
    __hip_bfloat16* __restrict__ Ctx)
{
  __shared__ __align__(16) __hip_bfloat16 Ks[2][64 * 64];   // [kv][dh] 8KB x2
  __shared__ __align__(16) __hip_bfloat16 Vs[2][64 * 64];   // [dh][kv] 8KB x2
  __shared__ __align__(16) unsigned short Pl[4][16 * 64];   // per-wave [q][kv] 2KB
  const int tid = threadIdx.x, lane = tid & 63, w = tid >> 6;
  const int r15 = lane & 15, g = lane >> 4;
  const int bh = blockIdx.y;
  const int b = bh >> 4, h = bh & 15;
  const int qb = blockIdx.x;
  const int q = qb * 64 + w * 16 + r15;        // this lane's q column
  const __hip_bfloat16* Qh = Qb  + (size_t)bh * S_ * DH_;
  const __hip_bfloat16* Kh = Kb  + (size_t)bh * S_ * DH_;
  const __hip_bfloat16* Vh = Vtb + (size_t)bh * DH_ * S_;
  char* PlW = (char*)&Pl[w][0];
  const int sw = (r15 & 7);                    // row-XOR swizzle key

  // Q fragment (B operand): col=q (lane), k = d = g*8+j
  bf16x8 qf[2];
  #pragma unroll
  for (int ks = 0; ks < 2; ++ks)
    qf[ks] = *reinterpret_cast<const bf16x8*>(Qh + (size_t)q * DH_ + ks * 32 + g * 8);

  // cooperative stage of one 64-kv tile: K [kv][dh] and Vt [dh][kv],
  // source pre-swizzled so LDS holds chunk c at slot c^(row&7)  [rule #21]
  auto stage = [&](int bufi, int t) {
    const int kv0 = t * 64;
    #pragma unroll
    for (int i = 0; i < 2; ++i) {
      const int c = i * 256 + tid;             // chunk 0..511 (16B each)
      const int r = c >> 3;
      const int scc = (c & 7) ^ (r & 7);
      const int cbase = i * 256 + w * 64;      // wave-uniform dest chunk base
      gld_lds16(Kh + (size_t)(kv0 + r) * DH_ + scc * 8, (void*)(Ks[bufi] + cbase * 8));
      gld_lds16(Vh + (size_t)r * S_ + kv0 + scc * 8,    (void*)(Vs[bufi] + cbase * 8));
    }
  };

  f32x4 of[4] = {};                            // O^T accum [dh-frag][reg]
  float mrow = -INFINITY, lrow = 0.f;

  const int nt = qb + 1;
  stage(0, 0);
  __syncthreads();

  for (int t = 0; t < nt; ++t) {
    const int cur = t & 1;
    if (t + 1 < nt) stage(cur ^ 1, t + 1);
    const char* Kb_ = (const char*)Ks[cur];
    const char* Vb_ = (const char*)Vs[cur];
    const int kv0 = t * 64;

    // QK^T swapped: sf[c] = K-tile-rows x Q-cols -> D[kv][q]
    f32x4 sf[4] = {};
    #pragma unroll
    for (int ks = 0; ks < 2; ++ks)
      #pragma unroll
      for (int c = 0; c < 4; ++c) {
        bf16x8 kf = *reinterpret_cast<const bf16x8*>(
            Kb_ + (c * 16 + r15) * 128 + (((ks * 4 + g) ^ sw) * 16));
        sf[c] = __builtin_amdgcn_mfma_f32_16x16x32_bf16(kf, qf[ks], sf[c], 0, 0, 0);
      }

    // lane-local online softmax for q = this lane's column
    float pv[16];
    const bool diag = (t == qb);
    #pragma unroll
    for (int c = 0; c < 4; ++c)
      #pragma unroll
      for (int r = 0; r < 4; ++r) {
        const int kv = kv0 + c * 16 + g * 4 + r;
        float v = sf[c][r];                    // Q was pre-scaled
        pv[c * 4 + r] = (diag && kv > q) ? -INFINITY : v;
      }
    float t8[8], t4[4];
    #pragma unroll
    for (int j = 0; j < 8; ++j) t8[j] = fmaxf(pv[j], pv[j + 8]);
    #pragma unroll
    for (int j = 0; j < 4; ++j) t4[j] = fmaxf(t8[j], t8[j + 4]);
    float vmax = fmaxf(fmaxf(t4[0], t4[1]), fmaxf(t4[2], t4[3]));
    vmax = fmaxf(vmax, __shfl_xor(vmax, 16, 64));
    vmax = fmaxf(vmax, __shfl_xor(vmax, 32, 64));
    const float mnew = fmaxf(mrow, vmax);
    const float a = __expf(mrow - mnew);       // exp(-inf)=0 on first tile
    float pe[16];
    #pragma unroll
    for (int j = 0; j < 16; ++j) pe[j] = __expf(pv[j] - mnew);
    // pack 4 consecutive kv (regs) into one 8B swizzled store
    #pragma unroll
    for (int c = 0; c < 4; ++c) {
      ushort4 pw;
      pw.x = f2bf(pe[c * 4 + 0]); pw.y = f2bf(pe[c * 4 + 1]);
      pw.z = f2bf(pe[c * 4 + 2]); pw.w = f2bf(pe[c * 4 + 3]);
      const int chunk = (c * 2 + (g >> 1)) ^ sw;
      *reinterpret_cast<ushort4*>(PlW + r15 * 128 + chunk * 16 + (g & 1) * 8) = pw;
    }
    float s8[8], s4[4];
    #pragma unroll
    for (int j = 0; j < 8; ++j) s8[j] = pe[j] + pe[j + 8];
    #pragma unroll
    for (int j = 0; j < 4; ++j) s4[j] = s8[j] + s8[j + 4];
    float psum = (s4[0] + s4[1]) + (s4[2] + s4[3]);
    psum += __shfl_xor(psum, 16, 64);
    psum += __shfl_xor(psum, 32, 64);
    lrow = lrow * a + psum;
    mrow = mnew;

    #pragma unroll
    for (int d = 0; d < 4; ++d)
      #pragma unroll
      for (int r = 0; r < 4; ++r) of[d][r] *= a;

    // PV: O^T[dh][q] += V^T-rows x P-cols
    #pragma unroll
    for (int ks = 0; ks < 2; ++ks) {
      bf16x8 pf = *reinterpret_cast<const bf16x8*>(
          PlW + r15 * 128 + (((ks * 4 + g) ^ sw) * 16));
      #pragma unroll
      for (int d = 0; d < 4; ++d) {
        bf16x8 vf = *reinterpret_cast<const bf16x8*>(
            Vb_ + (d * 16 + r15) * 128 + (((ks * 4 + g) ^ sw) * 16));
        of[d] = __builtin_amdgcn_mfma_f32_16x16x32_bf16(vf, pf, of[d], 0, 0, 0);
      }
    }
    __syncthreads();
  }

  // write ctx [b, s, h, dh] bf16; lane owns q col, dh = d*16 + g*4 + rr
  const float inv = 1.0f / lrow;
  unsigned short* Cp = (unsigned short*)Ctx + ((size_t)(b * S_ + q) * H_ + h) * DH_;
  #pragma unroll
  for (int d = 0; d < 4; ++d) {
    ushort4 ov;
    ov.x = f2bf(of[d][0] * inv); ov.y = f2bf(of[d][1] * inv);
    ov.z = f2bf(of[d][2] * inv); ov.w = f2bf(of[d][3] * inv);
    *reinterpret_cast<ushort4*>(Cp + d * 16 + g * 4) = ov;
  }
}

// --------------------------------- launch --------------------------------
extern "C" void kernel_launch(void* const* d_in, const int* in_sizes, int n_in,
                              void* d_out, int out_size, void* d_ws, size_t ws_size,
                              hipStream_t stream) {
  const float* x  = (const float*)d_in[0];
  const float* Wq = (const float*)d_in[1];
  const float* Wk = (const float*)d_in[2];
  const float* Wv = (const float*)d_in[3];
  const float* Wo = (const float*)d_in[4];
  const float* bo = (const float*)d_in[5];
  float* out = (float*)d_out;

  uint8_t* ws = (uint8_t*)d_ws;
  // layout (bytes): xb 8M | Wt3 6M | Wot 2M | Q 8M | K 8M | Vt 8M | Ctx 8M = 48MB
  __hip_bfloat16* xb  = (__hip_bfloat16*)(ws);
  __hip_bfloat16* Wt3 = (__hip_bfloat16*)(ws + 8388608);
  __hip_bfloat16* Wot = (__hip_bfloat16*)(ws + 14680064);
  __hip_bfloat16* Qb  = (__hip_bfloat16*)(ws + 16777216);
  __hip_bfloat16* Kb  = (__hip_bfloat16*)(ws + 25165824);
  __hip_bfloat16* Vtb = (__hip_bfloat16*)(ws + 33554432);
  __hip_bfloat16* Ctx = (__hip_bfloat16*)(ws + 41943040);

  k_convert_x<<<4096, 256, 0, stream>>>(x, (unsigned short*)xb);
  k_transpose_w<<<dim3(32, 32, 4), dim3(32, 8), 0, stream>>>(Wq, Wk, Wv, Wo, Wt3, Wot);
  // fused QKV: A = xb [4096,1024], Bt = [Wq^T|Wk^T|Wv^T] [3072,1024]
  k_gemm_bt<0><<<dim3(32, 24), 256, 0, stream>>>(xb, Wt3, Qb, Kb, Vtb, nullptr, nullptr,
                                                 4096, 3072, 1024);
  k_attn<<<dim3(32, 32), 256, 0, stream>>>(Qb, Kb, Vtb, Ctx);
  // out = Ctx @ Wo + bo  (fp32 out)
  k_gemm_bt<1><<<dim3(32, 8), 256, 0, stream>>>(Ctx, Wot, nullptr, nullptr, nullptr,
                                                out, bo, 4096, 1024, 1024);
}

// Round 3
// 129.381 us; speedup vs baseline: 2.3818x; 1.1890x over previous
//
#include <hip/hip_runtime.h>
#include <hip/hip_bf16.h>
#include <stdint.h>

// Problem constants
#define B_   2
#define S_   2048
#define DIN  1024
#define DOUT 1024
#define H_   16
#define DH_  64

typedef __bf16 bf16_t;
typedef bf16_t bf16x8 __attribute__((ext_vector_type(8)));
typedef float  f32x4  __attribute__((ext_vector_type(4)));

static __device__ __forceinline__ void gld_lds16(const void* g, void* l) {
  __builtin_amdgcn_global_load_lds((const __attribute__((address_space(1))) void*)g,
                                   (__attribute__((address_space(3))) void*)l, 16, 0, 0);
}

static __device__ __forceinline__ unsigned short f2bf(float f) {
  __hip_bfloat16 h = __float2bfloat16(f);
  return __builtin_bit_cast(unsigned short, h);
}

static __device__ __forceinline__ float fexp2(float x) {
#if __has_builtin(__builtin_amdgcn_exp2f)
  return __builtin_amdgcn_exp2f(x);
#else
  return exp2f(x);
#endif
}

// ---------------- convert x (fp32 -> bf16), 4 elems/thread ----------------
__global__ __launch_bounds__(256) void k_convert_x(const float* __restrict__ x,
                                                   unsigned short* __restrict__ xb) {
  int i = (blockIdx.x * 256 + threadIdx.x) * 4;
  float4 v = *reinterpret_cast<const float4*>(x + i);
  ushort4 o;
  o.x = f2bf(v.x); o.y = f2bf(v.y); o.z = f2bf(v.z); o.w = f2bf(v.w);
  *reinterpret_cast<ushort4*>(xb + i) = o;
}

// ------------- transpose+convert W [K][N] fp32 -> Wt [N][K] bf16 -----------
__global__ __launch_bounds__(256) void k_transpose_w(const float* __restrict__ Wq,
                                                     const float* __restrict__ Wk,
                                                     const float* __restrict__ Wv,
                                                     const float* __restrict__ Wo,
                                                     __hip_bfloat16* __restrict__ Wt3,
                                                     __hip_bfloat16* __restrict__ Wot) {
  __shared__ float tile[32][33];
  const int z = blockIdx.z;
  const float* src = (z == 0) ? Wq : (z == 1) ? Wk : (z == 2) ? Wv : Wo;
  __hip_bfloat16* dst = (z < 3) ? (Wt3 + (size_t)z * DIN * DOUT) : Wot;
  const int n0 = blockIdx.x * 32, k0 = blockIdx.y * 32;
  const int tx = threadIdx.x, ty = threadIdx.y;   // block (32,8)
  #pragma unroll
  for (int i = ty; i < 32; i += 8)
    tile[i][tx] = src[(size_t)(k0 + i) * DOUT + n0 + tx];
  __syncthreads();
  #pragma unroll
  for (int i = ty; i < 32; i += 8)
    dst[(size_t)(n0 + i) * DIN + k0 + tx] = __float2bfloat16(tile[tx][i]);
}

// ---------------- GEMM: C[M,N] = A[M,K] * Bt[N,K]^T  (bf16 MFMA) ----------
// MODE 0: epilogue scatters to Q*(scale*log2e) [b,h,s,dh], K [b,h,s,dh],
//         Vt [b,h,dh,s]   (exp2-domain softmax downstream)
// MODE 1: epilogue writes fp32 Out[m*N+n] + bias[n]
template <int MODE>
__global__ __launch_bounds__(256) void k_gemm_bt(
    const __hip_bfloat16* __restrict__ A,    // [M][K]
    const __hip_bfloat16* __restrict__ Bt,   // [N][K]
    __hip_bfloat16* __restrict__ Qb, __hip_bfloat16* __restrict__ Kb,
    __hip_bfloat16* __restrict__ Vtb,
    float* __restrict__ Out, const float* __restrict__ bias,
    int M, int N, int K)
{
  __shared__ __align__(16) __hip_bfloat16 As[128 * 32];
  __shared__ __align__(16) __hip_bfloat16 Bs[128 * 32];
  const int tid = threadIdx.x;
  const int lane = tid & 63, wid = tid >> 6;
  const int r15 = lane & 15, g = lane >> 4;
  const int m0 = blockIdx.x * 128, n0 = blockIdx.y * 128;
  const int wr = wid >> 1, wc = wid & 1;          // wave owns 64x64 sub-tile
  f32x4 acc[4][4] = {};

  for (int kt = 0; kt < K; kt += 32) {
    #pragma unroll
    for (int i = 0; i < 2; ++i) {
      const int li = i * 256 + tid;               // 0..511, 16B each
      const int row = li >> 2, kb = (li & 3) * 8; // kb in elements
      gld_lds16(A  + (size_t)(m0 + row) * K + kt + kb, (void*)(As + (size_t)(li & ~63) * 8));
      gld_lds16(Bt + (size_t)(n0 + row) * K + kt + kb, (void*)(Bs + (size_t)(li & ~63) * 8));
    }
    __syncthreads();
    bf16x8 af[4], bfr[4];
    #pragma unroll
    for (int mi = 0; mi < 4; ++mi)
      af[mi] = *reinterpret_cast<const bf16x8*>(As + (wr * 64 + mi * 16 + r15) * 32 + g * 8);
    #pragma unroll
    for (int ni = 0; ni < 4; ++ni)
      bfr[ni] = *reinterpret_cast<const bf16x8*>(Bs + (wc * 64 + ni * 16 + r15) * 32 + g * 8);
    #pragma unroll
    for (int mi = 0; mi < 4; ++mi)
      #pragma unroll
      for (int ni = 0; ni < 4; ++ni)
        acc[mi][ni] = __builtin_amdgcn_mfma_f32_16x16x32_bf16(af[mi], bfr[ni], acc[mi][ni], 0, 0, 0);
    __syncthreads();
  }

  // Epilogue. C/D layout: col = lane&15, row = (lane>>4)*4 + reg  [verified m89/m91]
  #pragma unroll
  for (int mi = 0; mi < 4; ++mi) {
    #pragma unroll
    for (int ni = 0; ni < 4; ++ni) {
      #pragma unroll
      for (int rr = 0; rr < 4; ++rr) {
        const int m = m0 + wr * 64 + mi * 16 + g * 4 + rr;
        const int n = n0 + wc * 64 + ni * 16 + r15;
        float v = acc[mi][ni][rr];
        if (MODE == 0) {
          const int w = n >> 10, nn = n & 1023;
          const int h = nn >> 6, dh = nn & 63;
          const int b = m >> 11, s = m & 2047;
          // fold 1/sqrt(S) * log2(e) into Q (softmax runs in exp2 domain)
          if (w == 0) v *= 0.022097086912079608f * 1.4426950408889634f;
          const __hip_bfloat16 hv = __float2bfloat16(v);
          const size_t bh = (size_t)(b * H_ + h);
          if (w == 0)      Qb [(bh * S_ + s) * DH_ + dh] = hv;
          else if (w == 1) Kb [(bh * S_ + s) * DH_ + dh] = hv;
          else             Vtb[(bh * DH_ + dh) * S_ + s] = hv;
        } else {
          Out[(size_t)m * N + n] = v + bias[n];
        }
      }
    }
  }
}

// ---------------- flash attention (causal, swapped-operand QK^T) ----------
// grid (B*H, S/128); bh is the FAST grid dim so blocks sharing a head's K/V
// land on the same XCD (id%8 == bh%8) -> K/V stays L2-resident per XCD.
// Each block processes TWO 64-row q-tiles: qa=blockIdx.y and 31-qa
// -> uniform 33 kv-tiles per block (causal load balance).
// 4 waves/block, each wave owns 16 q. KVBLK=64, K/V double-buffered in LDS.
// Swapped QK^T: D[kv][q], lane-local softmax in exp2 domain, T13 defer-rescale.
__global__ __launch_bounds__(256) void k_attn(
    const __hip_bfloat16* __restrict__ Qb,
    const __hip_bfloat16* __restrict__ Kb,
    const __hip_bfloat16* __restrict__ Vtb,
    __hip_bfloat16* __restrict__ Ctx)
{
  __shared__ __align__(16) __hip_bfloat16 Ks[2][64 * 64];   // [kv][dh] 8KB x2
  __shared__ __align__(16) __hip_bfloat16 Vs[2][64 * 64];   // [dh][kv] 8KB x2
  __shared__ __align__(16) unsigned short Pl[4][16 * 64];   // per-wave [q][kv] 2KB
  const int tid = threadIdx.x, lane = tid & 63, w = tid >> 6;
  const int r15 = lane & 15, g = lane >> 4;
  const int bh = blockIdx.x;                   // fast dim -> XCD locality
  const int b = bh >> 4, h = bh & 15;
  const __hip_bfloat16* Qh = Qb  + (size_t)bh * S_ * DH_;
  const __hip_bfloat16* Kh = Kb  + (size_t)bh * S_ * DH_;
  const __hip_bfloat16* Vh = Vtb + (size_t)bh * DH_ * S_;
  char* PlW = (char*)&Pl[w][0];
  const int sw = (r15 & 7);                    // row-XOR swizzle key

  auto stage = [&](int bufi, int t) {
    const int kv0 = t * 64;
    #pragma unroll
    for (int i = 0; i < 2; ++i) {
      const int c = i * 256 + tid;             // chunk 0..511 (16B each)
      const int r = c >> 3;
      const int scc = (c & 7) ^ (r & 7);       // pre-swizzled source [rule #21]
      const int cbase = i * 256 + w * 64;      // wave-uniform dest chunk base
      gld_lds16(Kh + (size_t)(kv0 + r) * DH_ + scc * 8, (void*)(Ks[bufi] + cbase * 8));
      gld_lds16(Vh + (size_t)r * S_ + kv0 + scc * 8,    (void*)(Vs[bufi] + cbase * 8));
    }
  };

  #pragma unroll 1
  for (int ph = 0; ph < 2; ++ph) {
    const int qb = ph ? (31 - blockIdx.y) : blockIdx.y;
    const int q = qb * 64 + w * 16 + r15;      // this lane's q column

    bf16x8 qf[2];
    #pragma unroll
    for (int ks = 0; ks < 2; ++ks)
      qf[ks] = *reinterpret_cast<const bf16x8*>(Qh + (size_t)q * DH_ + ks * 32 + g * 8);

    f32x4 of[4] = {};                          // O^T accum [dh-frag][reg]
    float mrow = -INFINITY, lrow = 0.f;

    const int nt = qb + 1;
    stage(0, 0);
    __syncthreads();

    for (int t = 0; t < nt; ++t) {
      const int cur = t & 1;
      if (t + 1 < nt) stage(cur ^ 1, t + 1);
      const char* Kb_ = (const char*)Ks[cur];
      const char* Vb_ = (const char*)Vs[cur];
      const int kv0 = t * 64;

      // QK^T swapped: sf[c] = K-rows x Q-cols -> D[kv][q]
      f32x4 sf[4] = {};
      __builtin_amdgcn_s_setprio(1);
      #pragma unroll
      for (int ks = 0; ks < 2; ++ks)
        #pragma unroll
        for (int c = 0; c < 4; ++c) {
          bf16x8 kf = *reinterpret_cast<const bf16x8*>(
              Kb_ + (c * 16 + r15) * 128 + (((ks * 4 + g) ^ sw) * 16));
          sf[c] = __builtin_amdgcn_mfma_f32_16x16x32_bf16(kf, qf[ks], sf[c], 0, 0, 0);
        }
      __builtin_amdgcn_s_setprio(0);

      // lane-local online softmax (exp2 domain; Q carries 1/sqrt(S)*log2e)
      float pv[16];
      const bool diag = (t == qb);
      #pragma unroll
      for (int c = 0; c < 4; ++c)
        #pragma unroll
        for (int r = 0; r < 4; ++r) {
          const int kv = kv0 + c * 16 + g * 4 + r;
          pv[c * 4 + r] = (diag && kv > q) ? -INFINITY : sf[c][r];
        }
      float t8[8], t4[4];
      #pragma unroll
      for (int j = 0; j < 8; ++j) t8[j] = fmaxf(pv[j], pv[j + 8]);
      #pragma unroll
      for (int j = 0; j < 4; ++j) t4[j] = fmaxf(t8[j], t8[j + 4]);
      float vmax = fmaxf(fmaxf(t4[0], t4[1]), fmaxf(t4[2], t4[3]));
      vmax = fmaxf(vmax, __shfl_xor(vmax, 16, 64));
      vmax = fmaxf(vmax, __shfl_xor(vmax, 32, 64));

      // T13 defer-rescale: only rescale when max grew by >8 (2^8=256 headroom)
      if (__any(vmax > mrow + 8.f)) {
        const float mnew = fmaxf(mrow, vmax);
        const float a = fexp2(mrow - mnew);    // exp2(-inf)=0 on first tile
        lrow *= a;
        #pragma unroll
        for (int d = 0; d < 4; ++d)
          #pragma unroll
          for (int r = 0; r < 4; ++r) of[d][r] *= a;
        mrow = mnew;
      }

      float pe[16];
      #pragma unroll
      for (int j = 0; j < 16; ++j) pe[j] = fexp2(pv[j] - mrow);
      #pragma unroll
      for (int c = 0; c < 4; ++c) {
        ushort4 pw;
        pw.x = f2bf(pe[c * 4 + 0]); pw.y = f2bf(pe[c * 4 + 1]);
        pw.z = f2bf(pe[c * 4 + 2]); pw.w = f2bf(pe[c * 4 + 3]);
        const int chunk = (c * 2 + (g >> 1)) ^ sw;
        *reinterpret_cast<ushort4*>(PlW + r15 * 128 + chunk * 16 + (g & 1) * 8) = pw;
      }
      float s8[8], s4[4];
      #pragma unroll
      for (int j = 0; j < 8; ++j) s8[j] = pe[j] + pe[j + 8];
      #pragma unroll
      for (int j = 0; j < 4; ++j) s4[j] = s8[j] + s8[j + 4];
      float psum = (s4[0] + s4[1]) + (s4[2] + s4[3]);
      psum += __shfl_xor(psum, 16, 64);
      psum += __shfl_xor(psum, 32, 64);
      lrow += psum;

      // PV: O^T[dh][q] += V^T-rows x P-cols
      __builtin_amdgcn_s_setprio(1);
      #pragma unroll
      for (int ks = 0; ks < 2; ++ks) {
        bf16x8 pf = *reinterpret_cast<const bf16x8*>(
            PlW + r15 * 128 + (((ks * 4 + g) ^ sw) * 16));
        #pragma unroll
        for (int d = 0; d < 4; ++d) {
          bf16x8 vf = *reinterpret_cast<const bf16x8*>(
              Vb_ + (d * 16 + r15) * 128 + (((ks * 4 + g) ^ sw) * 16));
          of[d] = __builtin_amdgcn_mfma_f32_16x16x32_bf16(vf, pf, of[d], 0, 0, 0);
        }
      }
      __builtin_amdgcn_s_setprio(0);
      __syncthreads();
    }

    // write ctx [b, s, h, dh] bf16; lane owns q col, dh = d*16 + g*4 + rr
    const float inv = 1.0f / lrow;
    unsigned short* Cp = (unsigned short*)Ctx + ((size_t)(b * S_ + q) * H_ + h) * DH_;
    #pragma unroll
    for (int d = 0; d < 4; ++d) {
      ushort4 ov;
      ov.x = f2bf(of[d][0] * inv); ov.y = f2bf(of[d][1] * inv);
      ov.z = f2bf(of[d][2] * inv); ov.w = f2bf(of[d][3] * inv);
      *reinterpret_cast<ushort4*>(Cp + d * 16 + g * 4) = ov;
    }
  }
}

// --------------------------------- launch --------------------------------
extern "C" void kernel_launch(void* const* d_in, const int* in_sizes, int n_in,
                              void* d_out, int out_size, void* d_ws, size_t ws_size,
                              hipStream_t stream) {
  const float* x  = (const float*)d_in[0];
  const float* Wq = (const float*)d_in[1];
  const float* Wk = (const float*)d_in[2];
  const float* Wv = (const float*)d_in[3];
  const float* Wo = (const float*)d_in[4];
  const float* bo = (const float*)d_in[5];
  float* out = (float*)d_out;

  uint8_t* ws = (uint8_t*)d_ws;
  // layout (bytes): xb 8M | Wt3 6M | Wot 2M | Q 8M | K 8M | Vt 8M | Ctx 8M = 48MB
  __hip_bfloat16* xb  = (__hip_bfloat16*)(ws);
  __hip_bfloat16* Wt3 = (__hip_bfloat16*)(ws + 8388608);
  __hip_bfloat16* Wot = (__hip_bfloat16*)(ws + 14680064);
  __hip_bfloat16* Qb  = (__hip_bfloat16*)(ws + 16777216);
  __hip_bfloat16* Kb  = (__hip_bfloat16*)(ws + 25165824);
  __hip_bfloat16* Vtb = (__hip_bfloat16*)(ws + 33554432);
  __hip_bfloat16* Ctx = (__hip_bfloat16*)(ws + 41943040);

  k_convert_x<<<4096, 256, 0, stream>>>(x, (unsigned short*)xb);
  k_transpose_w<<<dim3(32, 32, 4), dim3(32, 8), 0, stream>>>(Wq, Wk, Wv, Wo, Wt3, Wot);
  // fused QKV: A = xb [4096,1024], Bt = [Wq^T|Wk^T|Wv^T] [3072,1024]
  k_gemm_bt<0><<<dim3(32, 24), 256, 0, stream>>>(xb, Wt3, Qb, Kb, Vtb, nullptr, nullptr,
                                                 4096, 3072, 1024);
  k_attn<<<dim3(32, 16), 256, 0, stream>>>(Qb, Kb, Vtb, Ctx);
  // out = Ctx @ Wo + bo  (fp32 out)
  k_gemm_bt<1><<<dim3(32, 8), 256, 0, stream>>>(Ctx, Wot, nullptr, nullptr, nullptr,
                                                out, bo, 4096, 1024, 1024);
}

// Round 4
// 117.400 us; speedup vs baseline: 2.6249x; 1.1021x over previous
//
#include <hip/hip_runtime.h>
#include <hip/hip_bf16.h>
#include <stdint.h>

// Problem constants
#define B_   2
#define S_   2048
#define DIN  1024
#define DOUT 1024
#define H_   16
#define DH_  64

typedef __bf16 bf16_t;
typedef bf16_t bf16x8 __attribute__((ext_vector_type(8)));
typedef float  f32x4  __attribute__((ext_vector_type(4)));

static __device__ __forceinline__ void gld_lds16(const void* g, void* l) {
  __builtin_amdgcn_global_load_lds((const __attribute__((address_space(1))) void*)g,
                                   (__attribute__((address_space(3))) void*)l, 16, 0, 0);
}

static __device__ __forceinline__ unsigned short f2bf(float f) {
  __hip_bfloat16 h = __float2bfloat16(f);
  return __builtin_bit_cast(unsigned short, h);
}

static __device__ __forceinline__ float fexp2(float x) {
#if __has_builtin(__builtin_amdgcn_exp2f)
  return __builtin_amdgcn_exp2f(x);
#else
  return exp2f(x);
#endif
}

// ---------------- convert x (fp32 -> bf16), 4 elems/thread ----------------
__global__ __launch_bounds__(256) void k_convert_x(const float* __restrict__ x,
                                                   unsigned short* __restrict__ xb) {
  int i = (blockIdx.x * 256 + threadIdx.x) * 4;
  float4 v = *reinterpret_cast<const float4*>(x + i);
  ushort4 o;
  o.x = f2bf(v.x); o.y = f2bf(v.y); o.z = f2bf(v.z); o.w = f2bf(v.w);
  *reinterpret_cast<ushort4*>(xb + i) = o;
}

// ------------- transpose+convert W [K][N] fp32 -> Wt [N][K] bf16 -----------
__global__ __launch_bounds__(256) void k_transpose_w(const float* __restrict__ Wq,
                                                     const float* __restrict__ Wk,
                                                     const float* __restrict__ Wv,
                                                     const float* __restrict__ Wo,
                                                     __hip_bfloat16* __restrict__ Wt3,
                                                     __hip_bfloat16* __restrict__ Wot) {
  __shared__ float tile[32][33];
  const int z = blockIdx.z;
  const float* src = (z == 0) ? Wq : (z == 1) ? Wk : (z == 2) ? Wv : Wo;
  __hip_bfloat16* dst = (z < 3) ? (Wt3 + (size_t)z * DIN * DOUT) : Wot;
  const int n0 = blockIdx.x * 32, k0 = blockIdx.y * 32;
  const int tx = threadIdx.x, ty = threadIdx.y;   // block (32,8)
  #pragma unroll
  for (int i = ty; i < 32; i += 8)
    tile[i][tx] = src[(size_t)(k0 + i) * DOUT + n0 + tx];
  __syncthreads();
  #pragma unroll
  for (int i = ty; i < 32; i += 8)
    dst[(size_t)(n0 + i) * DIN + k0 + tx] = __float2bfloat16(tile[tx][i]);
}

// ---------------- GEMM: C[M,N] = A[M,K] * Bt[N,K]^T  (bf16 MFMA) ----------
// T3 minimum-2-phase: double-buffered LDS, stage(t+1) issued BEFORE the
// ds_read+MFMA of tile t, ONE barrier per iteration (its vmcnt(0) drain is
// covered by the MFMA cluster).
// MODE 0: epilogue scatters to Q*(scale*log2e) [b,h,s,dh], K [b,h,s,dh],
//         Vt [b,h,dh,s]   (exp2-domain softmax downstream)
// MODE 1: epilogue writes fp32 Out[m*N+n] + bias[n]
template <int MODE>
__global__ __launch_bounds__(256) void k_gemm_bt(
    const __hip_bfloat16* __restrict__ A,    // [M][K]
    const __hip_bfloat16* __restrict__ Bt,   // [N][K]
    __hip_bfloat16* __restrict__ Qb, __hip_bfloat16* __restrict__ Kb,
    __hip_bfloat16* __restrict__ Vtb,
    float* __restrict__ Out, const float* __restrict__ bias,
    int M, int N, int K)
{
  __shared__ __align__(16) __hip_bfloat16 As[2][128 * 32];
  __shared__ __align__(16) __hip_bfloat16 Bs[2][128 * 32];
  const int tid = threadIdx.x;
  const int lane = tid & 63, wid = tid >> 6;
  const int r15 = lane & 15, g = lane >> 4;
  const int m0 = blockIdx.x * 128, n0 = blockIdx.y * 128;
  const int wr = wid >> 1, wc = wid & 1;          // wave owns 64x64 sub-tile
  f32x4 acc[4][4] = {};

  auto stage = [&](int bi, int kt) {
    #pragma unroll
    for (int i = 0; i < 2; ++i) {
      const int c = i * 256 + tid;                // 0..511, 16B each
      const int row = c >> 2, kb = (c & 3) * 8;   // kb in elements
      gld_lds16(A  + (size_t)(m0 + row) * K + kt + kb, (void*)(As[bi] + (size_t)(c & ~63) * 8));
      gld_lds16(Bt + (size_t)(n0 + row) * K + kt + kb, (void*)(Bs[bi] + (size_t)(c & ~63) * 8));
    }
  };

  const int NT = K >> 5;                          // K-tiles of 32
  stage(0, 0);
  __syncthreads();                                // includes vmcnt(0) drain
  int bi = 0;
  for (int t = 0; t < NT; ++t) {
    if (t + 1 < NT) stage(bi ^ 1, (t + 1) * 32);  // prefetch BEFORE compute
    bf16x8 af[4], bfr[4];
    #pragma unroll
    for (int mi = 0; mi < 4; ++mi)
      af[mi] = *reinterpret_cast<const bf16x8*>(As[bi] + (wr * 64 + mi * 16 + r15) * 32 + g * 8);
    #pragma unroll
    for (int ni = 0; ni < 4; ++ni)
      bfr[ni] = *reinterpret_cast<const bf16x8*>(Bs[bi] + (wc * 64 + ni * 16 + r15) * 32 + g * 8);
    __builtin_amdgcn_s_setprio(1);
    #pragma unroll
    for (int mi = 0; mi < 4; ++mi)
      #pragma unroll
      for (int ni = 0; ni < 4; ++ni)
        acc[mi][ni] = __builtin_amdgcn_mfma_f32_16x16x32_bf16(af[mi], bfr[ni], acc[mi][ni], 0, 0, 0);
    __builtin_amdgcn_s_setprio(0);
    __syncthreads();                              // drains stage loads + LDS reads
    bi ^= 1;
  }

  // Epilogue. C/D layout: col = lane&15, row = (lane>>4)*4 + reg  [verified m89/m91]
  #pragma unroll
  for (int mi = 0; mi < 4; ++mi) {
    #pragma unroll
    for (int ni = 0; ni < 4; ++ni) {
      const int mb = m0 + wr * 64 + mi * 16 + g * 4;    // 4 consecutive m
      const int n  = n0 + wc * 64 + ni * 16 + r15;
      if (MODE == 0) {
        const int w = n >> 10, nn = n & 1023;           // wave-uniform per frag
        const int h = nn >> 6, dh = nn & 63;
        const int b = mb >> 11, s = mb & 2047;
        const size_t bh = (size_t)(b * H_ + h);
        if (w == 2) {
          // V: [b,h,dh,s] -> 4 consecutive s, one 8B store
          ushort4 pv;
          pv.x = f2bf(acc[mi][ni][0]); pv.y = f2bf(acc[mi][ni][1]);
          pv.z = f2bf(acc[mi][ni][2]); pv.w = f2bf(acc[mi][ni][3]);
          *reinterpret_cast<ushort4*>((unsigned short*)Vtb + (bh * DH_ + dh) * S_ + s) = pv;
        } else {
          #pragma unroll
          for (int rr = 0; rr < 4; ++rr) {
            float v = acc[mi][ni][rr];
            if (w == 0) v *= 0.022097086912079608f * 1.4426950408889634f;
            const __hip_bfloat16 hv = __float2bfloat16(v);
            if (w == 0) Qb[(bh * S_ + s + rr) * DH_ + dh] = hv;
            else        Kb[(bh * S_ + s + rr) * DH_ + dh] = hv;
          }
        }
      } else {
        #pragma unroll
        for (int rr = 0; rr < 4; ++rr)
          Out[(size_t)(mb + rr) * N + n] = acc[mi][ni][rr] + bias[n];
      }
    }
  }
}

// ---------------- flash attention (causal, swapped-operand QK^T) ----------
// grid (B*H, S/128); bh is the FAST grid dim so blocks sharing a head's K/V
// land on the same XCD (id%8 == bh%8) -> K/V stays L2-resident per XCD.
// Each block processes TWO 64-row q-tiles: qa=blockIdx.y and 31-qa
// -> uniform 33 kv-tiles per block (causal load balance).
// 4 waves/block, each wave owns 16 q. KVBLK=64, K/V double-buffered in LDS.
// Swapped QK^T: D[kv][q], lane-local softmax in exp2 domain, T13 defer-rescale.
__global__ __launch_bounds__(256) void k_attn(
    const __hip_bfloat16* __restrict__ Qb,
    const __hip_bfloat16* __restrict__ Kb,
    const __hip_bfloat16* __restrict__ Vtb,
    __hip_bfloat16* __restrict__ Ctx)
{
  __shared__ __align__(16) __hip_bfloat16 Ks[2][64 * 64];   // [kv][dh] 8KB x2
  __shared__ __align__(16) __hip_bfloat16 Vs[2][64 * 64];   // [dh][kv] 8KB x2
  __shared__ __align__(16) unsigned short Pl[4][16 * 64];   // per-wave [q][kv] 2KB
  const int tid = threadIdx.x, lane = tid & 63, w = tid >> 6;
  const int r15 = lane & 15, g = lane >> 4;
  const int bh = blockIdx.x;                   // fast dim -> XCD locality
  const int b = bh >> 4, h = bh & 15;
  const __hip_bfloat16* Qh = Qb  + (size_t)bh * S_ * DH_;
  const __hip_bfloat16* Kh = Kb  + (size_t)bh * S_ * DH_;
  const __hip_bfloat16* Vh = Vtb + (size_t)bh * DH_ * S_;
  char* PlW = (char*)&Pl[w][0];
  const int sw = (r15 & 7);                    // row-XOR swizzle key

  auto stage = [&](int bufi, int t) {
    const int kv0 = t * 64;
    #pragma unroll
    for (int i = 0; i < 2; ++i) {
      const int c = i * 256 + tid;             // chunk 0..511 (16B each)
      const int r = c >> 3;
      const int scc = (c & 7) ^ (r & 7);       // pre-swizzled source [rule #21]
      const int cbase = i * 256 + w * 64;      // wave-uniform dest chunk base
      gld_lds16(Kh + (size_t)(kv0 + r) * DH_ + scc * 8, (void*)(Ks[bufi] + cbase * 8));
      gld_lds16(Vh + (size_t)r * S_ + kv0 + scc * 8,    (void*)(Vs[bufi] + cbase * 8));
    }
  };

  #pragma unroll 1
  for (int ph = 0; ph < 2; ++ph) {
    const int qb = ph ? (31 - blockIdx.y) : blockIdx.y;
    const int q = qb * 64 + w * 16 + r15;      // this lane's q column

    bf16x8 qf[2];
    #pragma unroll
    for (int ks = 0; ks < 2; ++ks)
      qf[ks] = *reinterpret_cast<const bf16x8*>(Qh + (size_t)q * DH_ + ks * 32 + g * 8);

    f32x4 of[4] = {};                          // O^T accum [dh-frag][reg]
    float mrow = -INFINITY, lrow = 0.f;

    const int nt = qb + 1;
    stage(0, 0);
    __syncthreads();

    for (int t = 0; t < nt; ++t) {
      const int cur = t & 1;
      if (t + 1 < nt) stage(cur ^ 1, t + 1);
      const char* Kb_ = (const char*)Ks[cur];
      const char* Vb_ = (const char*)Vs[cur];
      const int kv0 = t * 64;

      // QK^T swapped: sf[c] = K-rows x Q-cols -> D[kv][q]
      f32x4 sf[4] = {};
      __builtin_amdgcn_s_setprio(1);
      #pragma unroll
      for (int ks = 0; ks < 2; ++ks)
        #pragma unroll
        for (int c = 0; c < 4; ++c) {
          bf16x8 kf = *reinterpret_cast<const bf16x8*>(
              Kb_ + (c * 16 + r15) * 128 + (((ks * 4 + g) ^ sw) * 16));
          sf[c] = __builtin_amdgcn_mfma_f32_16x16x32_bf16(kf, qf[ks], sf[c], 0, 0, 0);
        }
      __builtin_amdgcn_s_setprio(0);

      // lane-local online softmax (exp2 domain; Q carries 1/sqrt(S)*log2e)
      float pv[16];
      const bool diag = (t == qb);
      #pragma unroll
      for (int c = 0; c < 4; ++c)
        #pragma unroll
        for (int r = 0; r < 4; ++r) {
          const int kv = kv0 + c * 16 + g * 4 + r;
          pv[c * 4 + r] = (diag && kv > q) ? -INFINITY : sf[c][r];
        }
      float t8[8], t4[4];
      #pragma unroll
      for (int j = 0; j < 8; ++j) t8[j] = fmaxf(pv[j], pv[j + 8]);
      #pragma unroll
      for (int j = 0; j < 4; ++j) t4[j] = fmaxf(t8[j], t8[j + 4]);
      float vmax = fmaxf(fmaxf(t4[0], t4[1]), fmaxf(t4[2], t4[3]));
      vmax = fmaxf(vmax, __shfl_xor(vmax, 16, 64));
      vmax = fmaxf(vmax, __shfl_xor(vmax, 32, 64));

      // T13 defer-rescale: only rescale when max grew by >8 (2^8=256 headroom)
      if (__any(vmax > mrow + 8.f)) {
        const float mnew = fmaxf(mrow, vmax);
        const float a = fexp2(mrow - mnew);    // exp2(-inf)=0 on first tile
        lrow *= a;
        #pragma unroll
        for (int d = 0; d < 4; ++d)
          #pragma unroll
          for (int r = 0; r < 4; ++r) of[d][r] *= a;
        mrow = mnew;
      }

      float pe[16];
      #pragma unroll
      for (int j = 0; j < 16; ++j) pe[j] = fexp2(pv[j] - mrow);
      #pragma unroll
      for (int c = 0; c < 4; ++c) {
        ushort4 pw;
        pw.x = f2bf(pe[c * 4 + 0]); pw.y = f2bf(pe[c * 4 + 1]);
        pw.z = f2bf(pe[c * 4 + 2]); pw.w = f2bf(pe[c * 4 + 3]);
        const int chunk = (c * 2 + (g >> 1)) ^ sw;
        *reinterpret_cast<ushort4*>(PlW + r15 * 128 + chunk * 16 + (g & 1) * 8) = pw;
      }
      float s8[8], s4[4];
      #pragma unroll
      for (int j = 0; j < 8; ++j) s8[j] = pe[j] + pe[j + 8];
      #pragma unroll
      for (int j = 0; j < 4; ++j) s4[j] = s8[j] + s8[j + 4];
      float psum = (s4[0] + s4[1]) + (s4[2] + s4[3]);
      psum += __shfl_xor(psum, 16, 64);
      psum += __shfl_xor(psum, 32, 64);
      lrow += psum;

      // PV: O^T[dh][q] += V^T-rows x P-cols
      __builtin_amdgcn_s_setprio(1);
      #pragma unroll
      for (int ks = 0; ks < 2; ++ks) {
        bf16x8 pf = *reinterpret_cast<const bf16x8*>(
            PlW + r15 * 128 + (((ks * 4 + g) ^ sw) * 16));
        #pragma unroll
        for (int d = 0; d < 4; ++d) {
          bf16x8 vf = *reinterpret_cast<const bf16x8*>(
              Vb_ + (d * 16 + r15) * 128 + (((ks * 4 + g) ^ sw) * 16));
          of[d] = __builtin_amdgcn_mfma_f32_16x16x32_bf16(vf, pf, of[d], 0, 0, 0);
        }
      }
      __builtin_amdgcn_s_setprio(0);
      __syncthreads();
    }

    // write ctx [b, s, h, dh] bf16; lane owns q col, dh = d*16 + g*4 + rr
    const float inv = 1.0f / lrow;
    unsigned short* Cp = (unsigned short*)Ctx + ((size_t)(b * S_ + q) * H_ + h) * DH_;
    #pragma unroll
    for (int d = 0; d < 4; ++d) {
      ushort4 ov;
      ov.x = f2bf(of[d][0] * inv); ov.y = f2bf(of[d][1] * inv);
      ov.z = f2bf(of[d][2] * inv); ov.w = f2bf(of[d][3] * inv);
      *reinterpret_cast<ushort4*>(Cp + d * 16 + g * 4) = ov;
    }
  }
}

// --------------------------------- launch --------------------------------
extern "C" void kernel_launch(void* const* d_in, const int* in_sizes, int n_in,
                              void* d_out, int out_size, void* d_ws, size_t ws_size,
                              hipStream_t stream) {
  const float* x  = (const float*)d_in[0];
  const float* Wq = (const float*)d_in[1];
  const float* Wk = (const float*)d_in[2];
  const float* Wv = (const float*)d_in[3];
  const float* Wo = (const float*)d_in[4];
  const float* bo = (const float*)d_in[5];
  float* out = (float*)d_out;

  uint8_t* ws = (uint8_t*)d_ws;
  // layout (bytes): xb 8M | Wt3 6M | Wot 2M | Q 8M | K 8M | Vt 8M | Ctx 8M = 48MB
  __hip_bfloat16* xb  = (__hip_bfloat16*)(ws);
  __hip_bfloat16* Wt3 = (__hip_bfloat16*)(ws + 8388608);
  __hip_bfloat16* Wot = (__hip_bfloat16*)(ws + 14680064);
  __hip_bfloat16* Qb  = (__hip_bfloat16*)(ws + 16777216);
  __hip_bfloat16* Kb  = (__hip_bfloat16*)(ws + 25165824);
  __hip_bfloat16* Vtb = (__hip_bfloat16*)(ws + 33554432);
  __hip_bfloat16* Ctx = (__hip_bfloat16*)(ws + 41943040);

  k_convert_x<<<4096, 256, 0, stream>>>(x, (unsigned short*)xb);
  k_transpose_w<<<dim3(32, 32, 4), dim3(32, 8), 0, stream>>>(Wq, Wk, Wv, Wo, Wt3, Wot);
  // fused QKV: A = xb [4096,1024], Bt = [Wq^T|Wk^T|Wv^T] [3072,1024]
  k_gemm_bt<0><<<dim3(32, 24), 256, 0, stream>>>(xb, Wt3, Qb, Kb, Vtb, nullptr, nullptr,
                                                 4096, 3072, 1024);
  k_attn<<<dim3(32, 16), 256, 0, stream>>>(Qb, Kb, Vtb, Ctx);
  // out = Ctx @ Wo + bo  (fp32 out)
  k_gemm_bt<1><<<dim3(32, 8), 256, 0, stream>>>(Ctx, Wot, nullptr, nullptr, nullptr,
                                                out, bo, 4096, 1024, 1024);
}

// Round 5
// 117.275 us; speedup vs baseline: 2.6277x; 1.0011x over previous
//
#include <hip/hip_runtime.h>
#include <hip/hip_bf16.h>
#include <stdint.h>

// Problem constants
#define B_   2
#define S_   2048
#define DIN  1024
#define DOUT 1024
#define H_   16
#define DH_  64

typedef __bf16 bf16_t;
typedef bf16_t bf16x8 __attribute__((ext_vector_type(8)));
typedef float  f32x4  __attribute__((ext_vector_type(4)));

static __device__ __forceinline__ void gld_lds16(const void* g, void* l) {
  __builtin_amdgcn_global_load_lds((const __attribute__((address_space(1))) void*)g,
                                   (__attribute__((address_space(3))) void*)l, 16, 0, 0);
}

static __device__ __forceinline__ unsigned short f2bf(float f) {
  __hip_bfloat16 h = __float2bfloat16(f);
  return __builtin_bit_cast(unsigned short, h);
}

static __device__ __forceinline__ float fexp2(float x) {
#if __has_builtin(__builtin_amdgcn_exp2f)
  return __builtin_amdgcn_exp2f(x);
#else
  return exp2f(x);
#endif
}

// ---------------- convert x (fp32 -> bf16), 4 elems/thread ----------------
__global__ __launch_bounds__(256) void k_convert_x(const float* __restrict__ x,
                                                   unsigned short* __restrict__ xb) {
  int i = (blockIdx.x * 256 + threadIdx.x) * 4;
  float4 v = *reinterpret_cast<const float4*>(x + i);
  ushort4 o;
  o.x = f2bf(v.x); o.y = f2bf(v.y); o.z = f2bf(v.z); o.w = f2bf(v.w);
  *reinterpret_cast<ushort4*>(xb + i) = o;
}

// ------------- transpose+convert W [K][N] fp32 -> Wt [N][K] bf16 -----------
__global__ __launch_bounds__(256) void k_transpose_w(const float* __restrict__ Wq,
                                                     const float* __restrict__ Wk,
                                                     const float* __restrict__ Wv,
                                                     const float* __restrict__ Wo,
                                                     __hip_bfloat16* __restrict__ Wt3,
                                                     __hip_bfloat16* __restrict__ Wot) {
  __shared__ float tile[32][33];
  const int z = blockIdx.z;
  const float* src = (z == 0) ? Wq : (z == 1) ? Wk : (z == 2) ? Wv : Wo;
  __hip_bfloat16* dst = (z < 3) ? (Wt3 + (size_t)z * DIN * DOUT) : Wot;
  const int n0 = blockIdx.x * 32, k0 = blockIdx.y * 32;
  const int tx = threadIdx.x, ty = threadIdx.y;   // block (32,8)
  #pragma unroll
  for (int i = ty; i < 32; i += 8)
    tile[i][tx] = src[(size_t)(k0 + i) * DOUT + n0 + tx];
  __syncthreads();
  #pragma unroll
  for (int i = ty; i < 32; i += 8)
    dst[(size_t)(n0 + i) * DIN + k0 + tx] = __float2bfloat16(tile[tx][i]);
}

// ---------------- GEMM: C[M,N] = A[M,K] * Bt[N,K]^T  (bf16 MFMA) ----------
// T3 minimum-2-phase: double-buffered LDS, stage(t+1) issued BEFORE the
// ds_read+MFMA of tile t, ONE barrier per iteration.
// MODE 0: epilogue scatters to Q*(scale*log2e) [b,h,s,dh], K [b,h,s,dh],
//         Vt [b,h,dh,s]   (exp2-domain softmax downstream)
// MODE 1: epilogue writes fp32 Out[m*N+n] + bias[n]
template <int MODE>
__global__ __launch_bounds__(256) void k_gemm_bt(
    const __hip_bfloat16* __restrict__ A,    // [M][K]
    const __hip_bfloat16* __restrict__ Bt,   // [N][K]
    __hip_bfloat16* __restrict__ Qb, __hip_bfloat16* __restrict__ Kb,
    __hip_bfloat16* __restrict__ Vtb,
    float* __restrict__ Out, const float* __restrict__ bias,
    int M, int N, int K)
{
  __shared__ __align__(16) __hip_bfloat16 As[2][128 * 32];
  __shared__ __align__(16) __hip_bfloat16 Bs[2][128 * 32];
  const int tid = threadIdx.x;
  const int lane = tid & 63, wid = tid >> 6;
  const int r15 = lane & 15, g = lane >> 4;
  const int m0 = blockIdx.x * 128, n0 = blockIdx.y * 128;
  const int wr = wid >> 1, wc = wid & 1;          // wave owns 64x64 sub-tile
  f32x4 acc[4][4] = {};

  auto stage = [&](int bi, int kt) {
    #pragma unroll
    for (int i = 0; i < 2; ++i) {
      const int c = i * 256 + tid;                // 0..511, 16B each
      const int row = c >> 2, kb = (c & 3) * 8;   // kb in elements
      gld_lds16(A  + (size_t)(m0 + row) * K + kt + kb, (void*)(As[bi] + (size_t)(c & ~63) * 8));
      gld_lds16(Bt + (size_t)(n0 + row) * K + kt + kb, (void*)(Bs[bi] + (size_t)(c & ~63) * 8));
    }
  };

  const int NT = K >> 5;                          // K-tiles of 32
  stage(0, 0);
  __syncthreads();                                // includes vmcnt(0) drain
  int bi = 0;
  for (int t = 0; t < NT; ++t) {
    if (t + 1 < NT) stage(bi ^ 1, (t + 1) * 32);  // prefetch BEFORE compute
    bf16x8 af[4], bfr[4];
    #pragma unroll
    for (int mi = 0; mi < 4; ++mi)
      af[mi] = *reinterpret_cast<const bf16x8*>(As[bi] + (wr * 64 + mi * 16 + r15) * 32 + g * 8);
    #pragma unroll
    for (int ni = 0; ni < 4; ++ni)
      bfr[ni] = *reinterpret_cast<const bf16x8*>(Bs[bi] + (wc * 64 + ni * 16 + r15) * 32 + g * 8);
    __builtin_amdgcn_s_setprio(1);
    #pragma unroll
    for (int mi = 0; mi < 4; ++mi)
      #pragma unroll
      for (int ni = 0; ni < 4; ++ni)
        acc[mi][ni] = __builtin_amdgcn_mfma_f32_16x16x32_bf16(af[mi], bfr[ni], acc[mi][ni], 0, 0, 0);
    __builtin_amdgcn_s_setprio(0);
    __syncthreads();                              // drains stage loads + LDS reads
    bi ^= 1;
  }

  // Epilogue. C/D layout: col = lane&15, row = (lane>>4)*4 + reg  [verified m89/m91]
  #pragma unroll
  for (int mi = 0; mi < 4; ++mi) {
    #pragma unroll
    for (int ni = 0; ni < 4; ++ni) {
      const int mb = m0 + wr * 64 + mi * 16 + g * 4;    // 4 consecutive m
      const int n  = n0 + wc * 64 + ni * 16 + r15;
      if (MODE == 0) {
        const int w = n >> 10, nn = n & 1023;           // wave-uniform per frag
        const int h = nn >> 6, dh = nn & 63;
        const int b = mb >> 11, s = mb & 2047;
        const size_t bh = (size_t)(b * H_ + h);
        if (w == 2) {
          // V: [b,h,dh,s] -> 4 consecutive s, one 8B store
          ushort4 pv;
          pv.x = f2bf(acc[mi][ni][0]); pv.y = f2bf(acc[mi][ni][1]);
          pv.z = f2bf(acc[mi][ni][2]); pv.w = f2bf(acc[mi][ni][3]);
          *reinterpret_cast<ushort4*>((unsigned short*)Vtb + (bh * DH_ + dh) * S_ + s) = pv;
        } else {
          #pragma unroll
          for (int rr = 0; rr < 4; ++rr) {
            float v = acc[mi][ni][rr];
            if (w == 0) v *= 0.022097086912079608f * 1.4426950408889634f;
            const __hip_bfloat16 hv = __float2bfloat16(v);
            if (w == 0) Qb[(bh * S_ + s + rr) * DH_ + dh] = hv;
            else        Kb[(bh * S_ + s + rr) * DH_ + dh] = hv;
          }
        }
      } else {
        #pragma unroll
        for (int rr = 0; rr < 4; ++rr)
          Out[(size_t)(mb + rr) * N + n] = acc[mi][ni][rr] + bias[n];
      }
    }
  }
}

// ---------------- flash attention (causal, swapped-operand QK^T) ----------
// grid (B*H, S/64); bh FAST dim -> XCD affinity (id%8==bh%8), K/V L2-resident.
// ONE 64-row q-tile per block, qb = 31 - blockIdx.y (HEAVY blocks dispatch
// first; light ones backfill the tail). 1024 blocks = 4 blocks/CU (LDS 40KB)
// = 16 waves/CU -> 2x the latency hiding of the paired-block variant.
// 4 waves/block, each wave owns 16 q. KVBLK=64, K/V double-buffered in LDS.
// Swapped QK^T: D[kv][q], lane-local softmax in exp2 domain, T13 defer-rescale.
// Causal cndmask generation only on the (wave-uniform) diagonal tile.
__global__ __launch_bounds__(256) void k_attn(
    const __hip_bfloat16* __restrict__ Qb,
    const __hip_bfloat16* __restrict__ Kb,
    const __hip_bfloat16* __restrict__ Vtb,
    __hip_bfloat16* __restrict__ Ctx)
{
  __shared__ __align__(16) __hip_bfloat16 Ks[2][64 * 64];   // [kv][dh] 8KB x2
  __shared__ __align__(16) __hip_bfloat16 Vs[2][64 * 64];   // [dh][kv] 8KB x2
  __shared__ __align__(16) unsigned short Pl[4][16 * 64];   // per-wave [q][kv] 2KB
  const int tid = threadIdx.x, lane = tid & 63, w = tid >> 6;
  const int r15 = lane & 15, g = lane >> 4;
  const int bh = blockIdx.x;                   // fast dim -> XCD locality
  const int b = bh >> 4, h = bh & 15;
  const int qb = 31 - blockIdx.y;              // heavy-first dispatch order
  const __hip_bfloat16* Qh = Qb  + (size_t)bh * S_ * DH_;
  const __hip_bfloat16* Kh = Kb  + (size_t)bh * S_ * DH_;
  const __hip_bfloat16* Vh = Vtb + (size_t)bh * DH_ * S_;
  char* PlW = (char*)&Pl[w][0];
  const int sw = (r15 & 7);                    // row-XOR swizzle key

  auto stage = [&](int bufi, int t) {
    const int kv0 = t * 64;
    #pragma unroll
    for (int i = 0; i < 2; ++i) {
      const int c = i * 256 + tid;             // chunk 0..511 (16B each)
      const int r = c >> 3;
      const int scc = (c & 7) ^ (r & 7);       // pre-swizzled source [rule #21]
      const int cbase = i * 256 + w * 64;      // wave-uniform dest chunk base
      gld_lds16(Kh + (size_t)(kv0 + r) * DH_ + scc * 8, (void*)(Ks[bufi] + cbase * 8));
      gld_lds16(Vh + (size_t)r * S_ + kv0 + scc * 8,    (void*)(Vs[bufi] + cbase * 8));
    }
  };

  const int q = qb * 64 + w * 16 + r15;        // this lane's q column

  bf16x8 qf[2];
  #pragma unroll
  for (int ks = 0; ks < 2; ++ks)
    qf[ks] = *reinterpret_cast<const bf16x8*>(Qh + (size_t)q * DH_ + ks * 32 + g * 8);

  f32x4 of[4] = {};                            // O^T accum [dh-frag][reg]
  float mrow = -INFINITY, lrow = 0.f;

  const int nt = qb + 1;
  stage(0, 0);
  __syncthreads();

  for (int t = 0; t < nt; ++t) {
    const int cur = t & 1;
    if (t + 1 < nt) stage(cur ^ 1, t + 1);
    const char* Kb_ = (const char*)Ks[cur];
    const char* Vb_ = (const char*)Vs[cur];
    const int kv0 = t * 64;

    // QK^T swapped: sf[c] = K-rows x Q-cols -> D[kv][q]
    f32x4 sf[4] = {};
    __builtin_amdgcn_s_setprio(1);
    #pragma unroll
    for (int ks = 0; ks < 2; ++ks)
      #pragma unroll
      for (int c = 0; c < 4; ++c) {
        bf16x8 kf = *reinterpret_cast<const bf16x8*>(
            Kb_ + (c * 16 + r15) * 128 + (((ks * 4 + g) ^ sw) * 16));
        sf[c] = __builtin_amdgcn_mfma_f32_16x16x32_bf16(kf, qf[ks], sf[c], 0, 0, 0);
      }
    __builtin_amdgcn_s_setprio(0);

    // lane-local online softmax (exp2 domain; Q carries 1/sqrt(S)*log2e)
    float pv[16];
    #pragma unroll
    for (int c = 0; c < 4; ++c)
      #pragma unroll
      for (int r = 0; r < 4; ++r)
        pv[c * 4 + r] = sf[c][r];
    if (t == qb) {                             // wave-uniform diagonal branch
      #pragma unroll
      for (int c = 0; c < 4; ++c)
        #pragma unroll
        for (int r = 0; r < 4; ++r) {
          const int kv = kv0 + c * 16 + g * 4 + r;
          if (kv > q) pv[c * 4 + r] = -INFINITY;
        }
    }
    float t8[8], t4[4];
    #pragma unroll
    for (int j = 0; j < 8; ++j) t8[j] = fmaxf(pv[j], pv[j + 8]);
    #pragma unroll
    for (int j = 0; j < 4; ++j) t4[j] = fmaxf(t8[j], t8[j + 4]);
    float vmax = fmaxf(fmaxf(t4[0], t4[1]), fmaxf(t4[2], t4[3]));
    vmax = fmaxf(vmax, __shfl_xor(vmax, 16, 64));
    vmax = fmaxf(vmax, __shfl_xor(vmax, 32, 64));

    // T13 defer-rescale: only rescale when max grew by >8 (2^8=256 headroom)
    if (__any(vmax > mrow + 8.f)) {
      const float mnew = fmaxf(mrow, vmax);
      const float a = fexp2(mrow - mnew);      // exp2(-inf)=0 on first tile
      lrow *= a;
      #pragma unroll
      for (int d = 0; d < 4; ++d)
        #pragma unroll
        for (int r = 0; r < 4; ++r) of[d][r] *= a;
      mrow = mnew;
    }

    float pe[16];
    #pragma unroll
    for (int j = 0; j < 16; ++j) pe[j] = fexp2(pv[j] - mrow);
    #pragma unroll
    for (int c = 0; c < 4; ++c) {
      ushort4 pw;
      pw.x = f2bf(pe[c * 4 + 0]); pw.y = f2bf(pe[c * 4 + 1]);
      pw.z = f2bf(pe[c * 4 + 2]); pw.w = f2bf(pe[c * 4 + 3]);
      const int chunk = (c * 2 + (g >> 1)) ^ sw;
      *reinterpret_cast<ushort4*>(PlW + r15 * 128 + chunk * 16 + (g & 1) * 8) = pw;
    }
    float s8[8], s4[4];
    #pragma unroll
    for (int j = 0; j < 8; ++j) s8[j] = pe[j] + pe[j + 8];
    #pragma unroll
    for (int j = 0; j < 4; ++j) s4[j] = s8[j] + s8[j + 4];
    float psum = (s4[0] + s4[1]) + (s4[2] + s4[3]);
    psum += __shfl_xor(psum, 16, 64);
    psum += __shfl_xor(psum, 32, 64);
    lrow += psum;

    // PV: O^T[dh][q] += V^T-rows x P-cols
    __builtin_amdgcn_s_setprio(1);
    #pragma unroll
    for (int ks = 0; ks < 2; ++ks) {
      bf16x8 pf = *reinterpret_cast<const bf16x8*>(
          PlW + r15 * 128 + (((ks * 4 + g) ^ sw) * 16));
      #pragma unroll
      for (int d = 0; d < 4; ++d) {
        bf16x8 vf = *reinterpret_cast<const bf16x8*>(
            Vb_ + (d * 16 + r15) * 128 + (((ks * 4 + g) ^ sw) * 16));
        of[d] = __builtin_amdgcn_mfma_f32_16x16x32_bf16(vf, pf, of[d], 0, 0, 0);
      }
    }
    __builtin_amdgcn_s_setprio(0);
    __syncthreads();
  }

  // write ctx [b, s, h, dh] bf16; lane owns q col, dh = d*16 + g*4 + rr
  const float inv = 1.0f / lrow;
  unsigned short* Cp = (unsigned short*)Ctx + ((size_t)(b * S_ + q) * H_ + h) * DH_;
  #pragma unroll
  for (int d = 0; d < 4; ++d) {
    ushort4 ov;
    ov.x = f2bf(of[d][0] * inv); ov.y = f2bf(of[d][1] * inv);
    ov.z = f2bf(of[d][2] * inv); ov.w = f2bf(of[d][3] * inv);
    *reinterpret_cast<ushort4*>(Cp + d * 16 + g * 4) = ov;
  }
}

// --------------------------------- launch --------------------------------
extern "C" void kernel_launch(void* const* d_in, const int* in_sizes, int n_in,
                              void* d_out, int out_size, void* d_ws, size_t ws_size,
                              hipStream_t stream) {
  const float* x  = (const float*)d_in[0];
  const float* Wq = (const float*)d_in[1];
  const float* Wk = (const float*)d_in[2];
  const float* Wv = (const float*)d_in[3];
  const float* Wo = (const float*)d_in[4];
  const float* bo = (const float*)d_in[5];
  float* out = (float*)d_out;

  uint8_t* ws = (uint8_t*)d_ws;
  // layout (bytes): xb 8M | Wt3 6M | Wot 2M | Q 8M | K 8M | Vt 8M | Ctx 8M = 48MB
  __hip_bfloat16* xb  = (__hip_bfloat16*)(ws);
  __hip_bfloat16* Wt3 = (__hip_bfloat16*)(ws + 8388608);
  __hip_bfloat16* Wot = (__hip_bfloat16*)(ws + 14680064);
  __hip_bfloat16* Qb  = (__hip_bfloat16*)(ws + 16777216);
  __hip_bfloat16* Kb  = (__hip_bfloat16*)(ws + 25165824);
  __hip_bfloat16* Vtb = (__hip_bfloat16*)(ws + 33554432);
  __hip_bfloat16* Ctx = (__hip_bfloat16*)(ws + 41943040);

  k_convert_x<<<4096, 256, 0, stream>>>(x, (unsigned short*)xb);
  k_transpose_w<<<dim3(32, 32, 4), dim3(32, 8), 0, stream>>>(Wq, Wk, Wv, Wo, Wt3, Wot);
  // fused QKV: A = xb [4096,1024], Bt = [Wq^T|Wk^T|Wv^T] [3072,1024]
  k_gemm_bt<0><<<dim3(32, 24), 256, 0, stream>>>(xb, Wt3, Qb, Kb, Vtb, nullptr, nullptr,
                                                 4096, 3072, 1024);
  k_attn<<<dim3(32, 32), 256, 0, stream>>>(Qb, Kb, Vtb, Ctx);
  // out = Ctx @ Wo + bo  (fp32 out)
  k_gemm_bt<1><<<dim3(32, 8), 256, 0, stream>>>(Ctx, Wot, nullptr, nullptr, nullptr,
                                                out, bo, 4096, 1024, 1024);
}